// Round 2
// baseline (1351.608 us; speedup 1.0000x reference)
//
#include <hip/hip_runtime.h>
#include <hip/hip_bf16.h>

#define D 128

typedef __attribute__((ext_vector_type(8))) short bf16x8;
typedef __attribute__((ext_vector_type(4))) float f32x4;

__device__ __forceinline__ float bf2f(ushort u) { return __uint_as_float(((unsigned)u) << 16); }
__device__ __forceinline__ ushort f2bf(float f) {
  unsigned x = __float_as_uint(f);
  x += 0x7fffu + ((x >> 16) & 1u);
  return (ushort)(x >> 16);
}

// ---------------- dtype probe: flag=1 if h is packed bf16, 0 if f32 ----------------
// bits 14..7 of each 32-bit word: bf16-pair -> exponent field of the low bf16
// (concentrated ~[0x60,0x8F] for N(0,1) data); f32 -> uniform mantissa bits (~19% hit).
__global__ void detect_kernel(const unsigned* __restrict__ h, int* __restrict__ flag) {
  __shared__ int cnt;
  int t = threadIdx.x;
  if (t == 0) cnt = 0;
  __syncthreads();
  unsigned e = (h[t] >> 7) & 0xFFu;
  int ok = (e >= 0x60u && e <= 0x8Fu) ? 1 : 0;
  atomicAdd(&cnt, ok);
  __syncthreads();
  if (t == 0) *flag = (cnt >= 128) ? 1 : 0;
}

// ---------------- LayerNorm: one wave per row, 2 features per lane ----------------
__global__ __launch_bounds__(256) void ln_kernel(
    const void* __restrict__ hv, const void* __restrict__ gv,
    const void* __restrict__ bv, const int* __restrict__ flag,
    ushort* __restrict__ hn, int n)
{
  int row = blockIdx.x * 4 + (threadIdx.x >> 6);
  int lane = threadIdx.x & 63;
  if (row >= n) return;
  bool isbf = (*flag != 0);
  float x0, x1;
  if (isbf) {
    ushort2 u = ((const ushort2*)((const ushort*)hv + (size_t)row * D))[lane];
    x0 = bf2f(u.x); x1 = bf2f(u.y);
  } else {
    float2 u = ((const float2*)((const float*)hv + (size_t)row * D))[lane];
    x0 = u.x; x1 = u.y;
  }
  float s = x0 + x1, sq = x0 * x0 + x1 * x1;
#pragma unroll
  for (int m = 1; m < 64; m <<= 1) { s += __shfl_xor(s, m); sq += __shfl_xor(sq, m); }
  float mu  = s * (1.0f / D);
  float var = sq * (1.0f / D) - mu * mu;
  float inv = rsqrtf(var + 1e-5f);
  float g0, g1, b0, b1;
  if (isbf) {
    ushort2 g = ((const ushort2*)gv)[lane];
    ushort2 b = ((const ushort2*)bv)[lane];
    g0 = bf2f(g.x); g1 = bf2f(g.y); b0 = bf2f(b.x); b1 = bf2f(b.y);
  } else {
    float2 g = ((const float2*)gv)[lane];
    float2 b = ((const float2*)bv)[lane];
    g0 = g.x; g1 = g.y; b0 = b.x; b1 = b.y;
  }
  ushort2 o;
  o.x = f2bf((x0 - mu) * inv * g0 + b0);
  o.y = f2bf((x1 - mu) * inv * g1 + b1);
  ((ushort2*)(hn + (size_t)row * D))[lane] = o;
}

// ---------------- Scatter: 32 lanes per edge, 4 features per lane ----------------
__global__ __launch_bounds__(256) void scatter_kernel(
    const ushort* __restrict__ hn, const int* __restrict__ src,
    const int* __restrict__ dst, float* __restrict__ msg,
    int* __restrict__ deg, int nE)
{
  int t = blockIdx.x * 256 + threadIdx.x;
  int e = t >> 5, l = t & 31;
  if (e >= nE) return;
  int s = src[e], d = dst[e];
  ushort4 u = ((const ushort4*)(hn + (size_t)s * D))[l];
  float* o = msg + (size_t)d * D + l * 4;
  unsafeAtomicAdd(o + 0, bf2f(u.x));
  unsafeAtomicAdd(o + 1, bf2f(u.y));
  unsafeAtomicAdd(o + 2, bf2f(u.z));
  unsafeAtomicAdd(o + 3, bf2f(u.w));
  if (l == 0) atomicAdd(deg + d, 1);
}

// ---------------- GEMM: out = [hn | msg*invdeg] @ [W_self; W_neigh] + b ----------------
// mfma_f32_16x16x32_bf16. Block = 256 thr = 4 waves, each wave does 16 rows x 128 cols.
// A lane layout: row = lane&15, k = ks*32 + (lane>>4)*8 + b (b=0..7, contiguous)
// B lane layout: col = lane&15, k same                        (pre-swizzled in LDS)
// D lane layout: col = lane&15, row = 4*(lane>>4) + b         [m89-verified]
__global__ __launch_bounds__(256) void gemm_kernel(
    const ushort* __restrict__ hn, const float* __restrict__ msg,
    const int* __restrict__ deg, const void* __restrict__ Wselfv,
    const void* __restrict__ Wneighv, const void* __restrict__ biasv,
    const int* __restrict__ flag, void* __restrict__ outv, int n)
{
  __shared__ __align__(16) ushort WB[8][8][64][8];  // [ks][nt][lane][b] = 64 KB
  bool isbf = (*flag != 0);

  int t = threadIdx.x;
  for (int i = t; i < 4096; i += 256) {
    int ks = i >> 9;
    int nt = (i >> 6) & 7;
    int ln = i & 63;
    int col   = nt * 16 + (ln & 15);
    int kbase = ks * 32 + ((ln >> 4) << 3);
#pragma unroll
    for (int b2 = 0; b2 < 8; ++b2) {
      int k = kbase + b2;
      size_t idx = (k < D) ? ((size_t)k * D + col) : ((size_t)(k - D) * D + col);
      const void* W = (k < D) ? Wselfv : Wneighv;
      ushort w;
      if (isbf) w = ((const ushort*)W)[idx];
      else      w = f2bf(((const float*)W)[idx]);
      WB[ks][nt][ln][b2] = w;
    }
  }
  __syncthreads();

  int wave = t >> 6, lane = t & 63;
  int r0 = blockIdx.x * 64 + wave * 16;
  int ar = r0 + (lane & 15);
  int koff = (lane >> 4) << 3;
  bool av = ar < n;
  float invd = 1.0f;
  if (av) { int dg = deg[ar]; invd = 1.0f / (float)(dg > 1 ? dg : 1); }

  f32x4 acc[8];
#pragma unroll
  for (int nt = 0; nt < 8; ++nt) acc[nt] = (f32x4)0.0f;

  // K = 0..127 : hn (bf16 internal buffer)
#pragma unroll
  for (int ks = 0; ks < 4; ++ks) {
    bf16x8 a = (bf16x8)0;
    if (av) a = *reinterpret_cast<const bf16x8*>(hn + (size_t)ar * D + ks * 32 + koff);
#pragma unroll
    for (int nt = 0; nt < 8; ++nt) {
      bf16x8 bfr = *reinterpret_cast<const bf16x8*>(&WB[ks][nt][lane][0]);
      acc[nt] = __builtin_amdgcn_mfma_f32_16x16x32_bf16(a, bfr, acc[nt], 0, 0, 0);
    }
  }
  // K = 128..255 : msg * invdeg (f32 internal buffer -> bf16)
#pragma unroll
  for (int ks = 0; ks < 4; ++ks) {
    bf16x8 a = (bf16x8)0;
    if (av) {
      const float* mp = msg + (size_t)ar * D + ks * 32 + koff;
      float4 m0 = *(const float4*)(mp);
      float4 m1 = *(const float4*)(mp + 4);
      a[0] = (short)f2bf(m0.x * invd); a[1] = (short)f2bf(m0.y * invd);
      a[2] = (short)f2bf(m0.z * invd); a[3] = (short)f2bf(m0.w * invd);
      a[4] = (short)f2bf(m1.x * invd); a[5] = (short)f2bf(m1.y * invd);
      a[6] = (short)f2bf(m1.z * invd); a[7] = (short)f2bf(m1.w * invd);
    }
#pragma unroll
    for (int nt = 0; nt < 8; ++nt) {
      bf16x8 bfr = *reinterpret_cast<const bf16x8*>(&WB[4 + ks][nt][lane][0]);
      acc[nt] = __builtin_amdgcn_mfma_f32_16x16x32_bf16(a, bfr, acc[nt], 0, 0, 0);
    }
  }

  // epilogue: bias + store (D layout: col = lane&15, row = 4*(lane>>4)+b)
  int orow = r0 + ((lane >> 4) << 2);
  int ocol = lane & 15;
#pragma unroll
  for (int nt = 0; nt < 8; ++nt) {
    int co = nt * 16 + ocol;
    float bi = isbf ? bf2f(((const ushort*)biasv)[co]) : ((const float*)biasv)[co];
#pragma unroll
    for (int b2 = 0; b2 < 4; ++b2) {
      int ro = orow + b2;
      if (ro < n) {
        float v = acc[nt][b2] + bi;
        if (isbf) ((ushort*)outv)[(size_t)ro * D + co] = f2bf(v);
        else      ((float*)outv)[(size_t)ro * D + co]  = v;
      }
    }
  }
}

extern "C" void kernel_launch(void* const* d_in, const int* in_sizes, int n_in,
                              void* d_out, int out_size, void* d_ws, size_t ws_size,
                              hipStream_t stream) {
  const void* h      = d_in[0];
  const int*  src    = (const int*)d_in[1];
  const int*  dst    = (const int*)d_in[2];
  const void* gamma  = d_in[3];
  const void* beta   = d_in[4];
  const void* Wself  = d_in[5];
  const void* Wneigh = d_in[6];
  const void* bias   = d_in[7];

  int nNodes = in_sizes[0] / D;   // 100000
  int nEdges = in_sizes[1];       // 640000

  char* ws = (char*)d_ws;
  size_t hnBytes  = (size_t)nNodes * D * sizeof(ushort);
  size_t hnPad    = (hnBytes + 255) & ~(size_t)255;
  size_t msgBytes = (size_t)nNodes * D * sizeof(float);
  size_t msgPad   = (msgBytes + 255) & ~(size_t)255;
  size_t degBytes = (size_t)nNodes * sizeof(int);
  size_t degPad   = (degBytes + 255) & ~(size_t)255;
  ushort* hn  = (ushort*)ws;
  float*  msg = (float*)(ws + hnPad);
  int*    deg = (int*)(ws + hnPad + msgPad);
  int*    flag = (int*)(ws + hnPad + msgPad + degPad);

  hipMemsetAsync(msg, 0, msgBytes, stream);
  hipMemsetAsync(deg, 0, degBytes, stream);

  detect_kernel<<<1, 256, 0, stream>>>((const unsigned*)h, flag);

  ln_kernel<<<(nNodes + 3) / 4, 256, 0, stream>>>(h, gamma, beta, flag, hn, nNodes);

  int scatterBlocks = (nEdges * 32 + 255) / 256;
  scatter_kernel<<<scatterBlocks, 256, 0, stream>>>(hn, src, dst, msg, deg, nEdges);

  gemm_kernel<<<(nNodes + 63) / 64, 256, 0, stream>>>(hn, msg, deg, Wself, Wneigh,
                                                      bias, flag, d_out, nNodes);
}

// Round 3
// 194.481 us; speedup vs baseline: 6.9498x; 6.9498x over previous
//
#include <hip/hip_runtime.h>
#include <hip/hip_bf16.h>

#define D 128
#define CH 1024  // scan chunk per block

typedef __attribute__((ext_vector_type(8))) short bf16x8;
typedef __attribute__((ext_vector_type(4))) float f32x4;

__device__ __forceinline__ float bf2f(ushort u) { return __uint_as_float(((unsigned)u) << 16); }
__device__ __forceinline__ ushort f2bf(float f) {
  unsigned x = __float_as_uint(f);
  x += 0x7fffu + ((x >> 16) & 1u);
  return (ushort)(x >> 16);
}

// ---------------- dtype probe: flag=1 if h is packed bf16, 0 if f32 ----------------
__global__ void detect_kernel(const unsigned* __restrict__ h, int* __restrict__ flag) {
  __shared__ int cnt;
  int t = threadIdx.x;
  if (t == 0) cnt = 0;
  __syncthreads();
  unsigned e = (h[t] >> 7) & 0xFFu;
  int ok = (e >= 0x60u && e <= 0x8Fu) ? 1 : 0;
  atomicAdd(&cnt, ok);
  __syncthreads();
  if (t == 0) *flag = (cnt >= 128) ? 1 : 0;
}

// ---------------- CSR build ----------------
__global__ __launch_bounds__(256) void hist_kernel(const int* __restrict__ dst,
                                                   int* __restrict__ deg, int nE) {
  int e = blockIdx.x * 256 + threadIdx.x;
  if (e < nE) atomicAdd(&deg[dst[e]], 1);
}

__global__ __launch_bounds__(256) void scan_local(const int* __restrict__ deg,
                                                  int* __restrict__ off,
                                                  int* __restrict__ bsum, int n) {
  __shared__ int sh[256];
  int b = blockIdx.x, t = threadIdx.x;
  int base = b * CH + t * 4;
  int v[4];
#pragma unroll
  for (int i = 0; i < 4; ++i) v[i] = (base + i < n) ? deg[base + i] : 0;
  int tsum = v[0] + v[1] + v[2] + v[3];
  sh[t] = tsum;
  __syncthreads();
#pragma unroll
  for (int d = 1; d < 256; d <<= 1) {
    int x = (t >= d) ? sh[t - d] : 0;
    __syncthreads();
    sh[t] += x;
    __syncthreads();
  }
  if (t == 255) bsum[b] = sh[255];
  int run = sh[t] - tsum;  // exclusive within block
#pragma unroll
  for (int i = 0; i < 4; ++i) {
    if (base + i < n) off[base + i] = run;
    run += v[i];
  }
}

__global__ void scan_sums(int* __restrict__ bsum, int* __restrict__ off, int nb, int n) {
  __shared__ int sh[128];
  int t = threadIdx.x;
  int v = (t < nb) ? bsum[t] : 0;
  sh[t] = v;
  __syncthreads();
#pragma unroll
  for (int d = 1; d < 128; d <<= 1) {
    int x = (t >= d) ? sh[t - d] : 0;
    __syncthreads();
    sh[t] += x;
    __syncthreads();
  }
  if (t < nb) bsum[t] = sh[t] - v;  // exclusive block offsets
  if (t == 127) off[n] = sh[127];   // grand total
}

__global__ __launch_bounds__(256) void scan_add(int* __restrict__ off,
                                                const int* __restrict__ bsum,
                                                int* __restrict__ cursor, int n) {
  int i = blockIdx.x * 256 + threadIdx.x;
  if (i < n) {
    int v = off[i] + bsum[i >> 10];
    off[i] = v;
    cursor[i] = v;
  }
}

__global__ __launch_bounds__(256) void bucket_kernel(const int* __restrict__ src,
                                                     const int* __restrict__ dst,
                                                     int* __restrict__ cursor,
                                                     int* __restrict__ esrc, int nE) {
  int e = blockIdx.x * 256 + threadIdx.x;
  if (e < nE) {
    int p = atomicAdd(&cursor[dst[e]], 1);
    esrc[p] = src[e];
  }
}

// ---------------- LayerNorm: one wave per row -> hcat[:, 0:128] ----------------
__global__ __launch_bounds__(256) void ln_kernel(
    const void* __restrict__ hv, const void* __restrict__ gv,
    const void* __restrict__ bv, const int* __restrict__ flag,
    ushort* __restrict__ hcat, int n)
{
  int row = blockIdx.x * 4 + (threadIdx.x >> 6);
  int lane = threadIdx.x & 63;
  if (row >= n) return;
  bool isbf = (*flag != 0);
  float x0, x1;
  if (isbf) {
    ushort2 u = ((const ushort2*)((const ushort*)hv + (size_t)row * D))[lane];
    x0 = bf2f(u.x); x1 = bf2f(u.y);
  } else {
    float2 u = ((const float2*)((const float*)hv + (size_t)row * D))[lane];
    x0 = u.x; x1 = u.y;
  }
  float s = x0 + x1, sq = x0 * x0 + x1 * x1;
#pragma unroll
  for (int m = 1; m < 64; m <<= 1) { s += __shfl_xor(s, m); sq += __shfl_xor(sq, m); }
  float mu  = s * (1.0f / D);
  float var = sq * (1.0f / D) - mu * mu;
  float inv = rsqrtf(var + 1e-5f);
  float g0, g1, b0, b1;
  if (isbf) {
    ushort2 g = ((const ushort2*)gv)[lane];
    ushort2 b = ((const ushort2*)bv)[lane];
    g0 = bf2f(g.x); g1 = bf2f(g.y); b0 = bf2f(b.x); b1 = bf2f(b.y);
  } else {
    float2 g = ((const float2*)gv)[lane];
    float2 b = ((const float2*)bv)[lane];
    g0 = g.x; g1 = g.y; b0 = b.x; b1 = b.y;
  }
  ushort2 o;
  o.x = f2bf((x0 - mu) * inv * g0 + b0);
  o.y = f2bf((x1 - mu) * inv * g1 + b1);
  ((ushort2*)(hcat + (size_t)row * 256))[lane] = o;
}

// ---------------- Aggregate: one wave per node, gather CSR -> hcat[:, 128:256] ----------------
__global__ __launch_bounds__(256) void aggregate_kernel(
    ushort* __restrict__ hcat, const int* __restrict__ off,
    const int* __restrict__ esrc, int n)
{
  int node = blockIdx.x * 4 + (threadIdx.x >> 6);
  int lane = threadIdx.x & 63;
  if (node >= n) return;
  int d0 = off[node], d1 = off[node + 1];
  float a0 = 0.f, a1 = 0.f;
  int j = d0;
  for (; j + 1 < d1; j += 2) {
    int s0 = esrc[j], s1 = esrc[j + 1];
    ushort2 u0 = ((const ushort2*)(hcat + (size_t)s0 * 256))[lane];
    ushort2 u1 = ((const ushort2*)(hcat + (size_t)s1 * 256))[lane];
    a0 += bf2f(u0.x) + bf2f(u1.x);
    a1 += bf2f(u0.y) + bf2f(u1.y);
  }
  if (j < d1) {
    int s0 = esrc[j];
    ushort2 u0 = ((const ushort2*)(hcat + (size_t)s0 * 256))[lane];
    a0 += bf2f(u0.x);
    a1 += bf2f(u0.y);
  }
  int dg = d1 - d0;
  float invd = 1.0f / (float)(dg > 1 ? dg : 1);
  ushort2 o;
  o.x = f2bf(a0 * invd);
  o.y = f2bf(a1 * invd);
  ((ushort2*)(hcat + (size_t)node * 256 + D))[lane] = o;
}

// ---------------- W repack into MFMA fragment layout (one-shot, 64 KB) ----------------
// WF[ks][nt][lane][b] = W[k = ks*32 + (lane>>4)*8 + b][col = nt*16 + (lane&15)]
// ks<4 -> W_self, ks>=4 -> W_neigh (K-concat).
__global__ __launch_bounds__(256) void repack_kernel(
    const void* __restrict__ Wselfv, const void* __restrict__ Wneighv,
    const int* __restrict__ flag, ushort* __restrict__ WF)
{
  bool isbf = (*flag != 0);
  int i = blockIdx.x * 256 + threadIdx.x;  // 32768 elements
  int b2 = i & 7;
  int ln = (i >> 3) & 63;
  int nt = (i >> 9) & 7;
  int ks = i >> 12;
  int col = nt * 16 + (ln & 15);
  int k = ks * 32 + ((ln >> 4) << 3) + b2;
  size_t idx = (k < D) ? ((size_t)k * D + col) : ((size_t)(k - D) * D + col);
  const void* W = (k < D) ? Wselfv : Wneighv;
  ushort w;
  if (isbf) w = ((const ushort*)W)[idx];
  else      w = f2bf(((const float*)W)[idx]);
  WF[i] = w;
}

// ---------------- GEMM: out = hcat[n][256] @ WF + b ----------------
__global__ __launch_bounds__(256) void gemm_kernel(
    const ushort* __restrict__ hcat, const ushort* __restrict__ WF,
    const void* __restrict__ biasv, const int* __restrict__ flag,
    void* __restrict__ outv, int n)
{
  __shared__ __align__(16) ushort WB[8][8][64][8];  // 64 KB, fragment layout
  bool isbf = (*flag != 0);

  int t = threadIdx.x;
#pragma unroll
  for (int i = 0; i < 16; ++i) {
    int idx = i * 256 + t;  // 4096 vectors of 8 ushorts
    ((bf16x8*)WB)[idx] = ((const bf16x8*)WF)[idx];
  }
  __syncthreads();

  int wave = t >> 6, lane = t & 63;
  int r0 = blockIdx.x * 64 + wave * 16;
  int ar = r0 + (lane & 15);
  int koff = (lane >> 4) << 3;
  bool av = ar < n;

  f32x4 acc[8];
#pragma unroll
  for (int nt = 0; nt < 8; ++nt) acc[nt] = (f32x4)0.0f;

#pragma unroll
  for (int ks = 0; ks < 8; ++ks) {
    bf16x8 a = (bf16x8)0;
    if (av) a = *reinterpret_cast<const bf16x8*>(hcat + (size_t)ar * 256 + ks * 32 + koff);
#pragma unroll
    for (int nt = 0; nt < 8; ++nt) {
      bf16x8 bfr = *reinterpret_cast<const bf16x8*>(&WB[ks][nt][lane][0]);
      acc[nt] = __builtin_amdgcn_mfma_f32_16x16x32_bf16(a, bfr, acc[nt], 0, 0, 0);
    }
  }

  // D layout: col = lane&15, row = 4*(lane>>4)+b   [empirically verified r0->r2]
  int orow = r0 + ((lane >> 4) << 2);
  int ocol = lane & 15;
#pragma unroll
  for (int nt = 0; nt < 8; ++nt) {
    int co = nt * 16 + ocol;
    float bi = isbf ? bf2f(((const ushort*)biasv)[co]) : ((const float*)biasv)[co];
#pragma unroll
    for (int b2 = 0; b2 < 4; ++b2) {
      int ro = orow + b2;
      if (ro < n) {
        float v = acc[nt][b2] + bi;
        if (isbf) ((ushort*)outv)[(size_t)ro * D + co] = f2bf(v);
        else      ((float*)outv)[(size_t)ro * D + co]  = v;
      }
    }
  }
}

extern "C" void kernel_launch(void* const* d_in, const int* in_sizes, int n_in,
                              void* d_out, int out_size, void* d_ws, size_t ws_size,
                              hipStream_t stream) {
  const void* h      = d_in[0];
  const int*  src    = (const int*)d_in[1];
  const int*  dst    = (const int*)d_in[2];
  const void* gamma  = d_in[3];
  const void* beta   = d_in[4];
  const void* Wself  = d_in[5];
  const void* Wneigh = d_in[6];
  const void* bias   = d_in[7];

  int nNodes = in_sizes[0] / D;   // 100000
  int nEdges = in_sizes[1];       // 640000
  int nb = (nNodes + CH - 1) / CH;

  char* ws = (char*)d_ws;
  size_t p = 0;
  auto alloc = [&](size_t bytes) { char* r = ws + p; p = (p + bytes + 255) & ~(size_t)255; return r; };
  ushort* hcat  = (ushort*)alloc((size_t)nNodes * 256 * sizeof(ushort));  // 51.2 MB
  int*   off    = (int*)alloc((size_t)(nNodes + 1) * sizeof(int));
  int*   deg    = (int*)alloc((size_t)nNodes * sizeof(int));
  int*   cursor = (int*)alloc((size_t)nNodes * sizeof(int));
  int*   bsum   = (int*)alloc(1024);
  int*   esrc   = (int*)alloc((size_t)nEdges * sizeof(int));
  ushort* WF    = (ushort*)alloc(32768 * sizeof(ushort));
  int*   flag   = (int*)alloc(256);

  hipMemsetAsync(deg, 0, (size_t)nNodes * sizeof(int), stream);

  detect_kernel<<<1, 256, 0, stream>>>((const unsigned*)h, flag);

  hist_kernel<<<(nEdges + 255) / 256, 256, 0, stream>>>(dst, deg, nEdges);
  scan_local<<<nb, 256, 0, stream>>>(deg, off, bsum, nNodes);
  scan_sums<<<1, 128, 0, stream>>>(bsum, off, nb, nNodes);
  scan_add<<<(nNodes + 255) / 256, 256, 0, stream>>>(off, bsum, cursor, nNodes);
  bucket_kernel<<<(nEdges + 255) / 256, 256, 0, stream>>>(src, dst, cursor, esrc, nEdges);

  ln_kernel<<<(nNodes + 3) / 4, 256, 0, stream>>>(h, gamma, beta, flag, hcat, nNodes);

  repack_kernel<<<128, 256, 0, stream>>>(Wself, Wneigh, flag, WF);

  aggregate_kernel<<<(nNodes + 3) / 4, 256, 0, stream>>>(hcat, off, esrc, nNodes);

  gemm_kernel<<<(nNodes + 63) / 64, 256, 0, stream>>>(hcat, WF, bias, flag, d_out, nNodes);
}

// Round 8
// 193.320 us; speedup vs baseline: 6.9916x; 1.0060x over previous
//
#include <hip/hip_runtime.h>
#include <hip/hip_bf16.h>

#define D 128
#define CH 1024  // scan chunk per block

typedef __attribute__((ext_vector_type(8))) short bf16x8;
typedef __attribute__((ext_vector_type(4))) float f32x4;

__device__ __forceinline__ float bf2f(ushort u) { return __uint_as_float(((unsigned)u) << 16); }
__device__ __forceinline__ ushort f2bf(float f) {
  unsigned x = __float_as_uint(f);
  x += 0x7fffu + ((x >> 16) & 1u);
  return (ushort)(x >> 16);
}

// ---------------- dtype probe: flag=1 if h is packed bf16, 0 if f32 ----------------
__global__ void detect_kernel(const unsigned* __restrict__ h, int* __restrict__ flag) {
  __shared__ int cnt;
  int t = threadIdx.x;
  if (t == 0) cnt = 0;
  __syncthreads();
  unsigned e = (h[t] >> 7) & 0xFFu;
  int ok = (e >= 0x60u && e <= 0x8Fu) ? 1 : 0;
  atomicAdd(&cnt, ok);
  __syncthreads();
  if (t == 0) *flag = (cnt >= 128) ? 1 : 0;
}

// ---------------- CSR build ----------------
__global__ __launch_bounds__(256) void hist_kernel(const int* __restrict__ dst,
                                                   int* __restrict__ deg, int nE) {
  int e = blockIdx.x * 256 + threadIdx.x;
  if (e < nE) atomicAdd(&deg[dst[e]], 1);
}

__global__ __launch_bounds__(256) void scan_local(const int* __restrict__ deg,
                                                  int* __restrict__ off,
                                                  int* __restrict__ bsum, int n) {
  __shared__ int sh[256];
  int b = blockIdx.x, t = threadIdx.x;
  int base = b * CH + t * 4;
  int v[4];
#pragma unroll
  for (int i = 0; i < 4; ++i) v[i] = (base + i < n) ? deg[base + i] : 0;
  int tsum = v[0] + v[1] + v[2] + v[3];
  sh[t] = tsum;
  __syncthreads();
#pragma unroll
  for (int d = 1; d < 256; d <<= 1) {
    int x = (t >= d) ? sh[t - d] : 0;
    __syncthreads();
    sh[t] += x;
    __syncthreads();
  }
  if (t == 255) bsum[b] = sh[255];
  int run = sh[t] - tsum;  // exclusive within block
#pragma unroll
  for (int i = 0; i < 4; ++i) {
    if (base + i < n) off[base + i] = run;
    run += v[i];
  }
}

__global__ void scan_sums(int* __restrict__ bsum, int* __restrict__ off, int nb, int n) {
  __shared__ int sh[128];
  int t = threadIdx.x;
  int v = (t < nb) ? bsum[t] : 0;
  sh[t] = v;
  __syncthreads();
#pragma unroll
  for (int d = 1; d < 128; d <<= 1) {
    int x = (t >= d) ? sh[t - d] : 0;
    __syncthreads();
    sh[t] += x;
    __syncthreads();
  }
  if (t < nb) bsum[t] = sh[t] - v;
  if (t == 127) off[n] = sh[127];
}

__global__ __launch_bounds__(256) void scan_add(int* __restrict__ off,
                                                const int* __restrict__ bsum,
                                                int* __restrict__ cursor, int n) {
  int i = blockIdx.x * 256 + threadIdx.x;
  if (i < n) {
    int v = off[i] + bsum[i >> 10];
    off[i] = v;
    cursor[i] = v;
  }
}

__global__ __launch_bounds__(256) void bucket_kernel(const int* __restrict__ src,
                                                     const int* __restrict__ dst,
                                                     int* __restrict__ cursor,
                                                     int* __restrict__ esrc, int nE) {
  int e = blockIdx.x * 256 + threadIdx.x;
  if (e < nE) {
    int p = atomicAdd(&cursor[dst[e]], 1);
    esrc[p] = src[e];
  }
}

// ---------------- LayerNorm: one wave per row -> hcat[:, 0:128] ----------------
__global__ __launch_bounds__(256) void ln_kernel(
    const void* __restrict__ hv, const void* __restrict__ gv,
    const void* __restrict__ bv, const int* __restrict__ flag,
    ushort* __restrict__ hcat, int n)
{
  int row = blockIdx.x * 4 + (threadIdx.x >> 6);
  int lane = threadIdx.x & 63;
  if (row >= n) return;
  bool isbf = (*flag != 0);
  float x0, x1;
  if (isbf) {
    ushort2 u = ((const ushort2*)((const ushort*)hv + (size_t)row * D))[lane];
    x0 = bf2f(u.x); x1 = bf2f(u.y);
  } else {
    float2 u = ((const float2*)((const float*)hv + (size_t)row * D))[lane];
    x0 = u.x; x1 = u.y;
  }
  float s = x0 + x1, sq = x0 * x0 + x1 * x1;
#pragma unroll
  for (int m = 1; m < 64; m <<= 1) { s += __shfl_xor(s, m); sq += __shfl_xor(sq, m); }
  float mu  = s * (1.0f / D);
  float var = sq * (1.0f / D) - mu * mu;
  float inv = rsqrtf(var + 1e-5f);
  float g0, g1, b0, b1;
  if (isbf) {
    ushort2 g = ((const ushort2*)gv)[lane];
    ushort2 b = ((const ushort2*)bv)[lane];
    g0 = bf2f(g.x); g1 = bf2f(g.y); b0 = bf2f(b.x); b1 = bf2f(b.y);
  } else {
    float2 g = ((const float2*)gv)[lane];
    float2 b = ((const float2*)bv)[lane];
    g0 = g.x; g1 = g.y; b0 = b.x; b1 = b.y;
  }
  ushort2 o;
  o.x = f2bf((x0 - mu) * inv * g0 + b0);
  o.y = f2bf((x1 - mu) * inv * g1 + b1);
  ((ushort2*)(hcat + (size_t)row * 256))[lane] = o;
}

// ---------------- Aggregate: one wave per node, unroll-4 gather -> hcat[:, 128:256] ----------------
__global__ __launch_bounds__(256) void aggregate_kernel(
    ushort* __restrict__ hcat, const int* __restrict__ off,
    const int* __restrict__ esrc, int n)
{
  int node = blockIdx.x * 4 + (threadIdx.x >> 6);
  int lane = threadIdx.x & 63;
  if (node >= n) return;
  int d0 = off[node], d1 = off[node + 1];
  float a0 = 0.f, a1 = 0.f;
  int j = d0;
  for (; j + 3 < d1; j += 4) {
    int s0 = esrc[j], s1 = esrc[j + 1], s2 = esrc[j + 2], s3 = esrc[j + 3];
    ushort2 u0 = ((const ushort2*)(hcat + (size_t)s0 * 256))[lane];
    ushort2 u1 = ((const ushort2*)(hcat + (size_t)s1 * 256))[lane];
    ushort2 u2 = ((const ushort2*)(hcat + (size_t)s2 * 256))[lane];
    ushort2 u3 = ((const ushort2*)(hcat + (size_t)s3 * 256))[lane];
    a0 += (bf2f(u0.x) + bf2f(u1.x)) + (bf2f(u2.x) + bf2f(u3.x));
    a1 += (bf2f(u0.y) + bf2f(u1.y)) + (bf2f(u2.y) + bf2f(u3.y));
  }
  for (; j < d1; ++j) {
    int s0 = esrc[j];
    ushort2 u0 = ((const ushort2*)(hcat + (size_t)s0 * 256))[lane];
    a0 += bf2f(u0.x);
    a1 += bf2f(u0.y);
  }
  int dg = d1 - d0;
  float invd = 1.0f / (float)(dg > 1 ? dg : 1);
  ushort2 o;
  o.x = f2bf(a0 * invd);
  o.y = f2bf(a1 * invd);
  ((ushort2*)(hcat + (size_t)node * 256 + D))[lane] = o;
}

// ---------------- W repack into MFMA fragment layout (one-shot, 64 KB) ----------------
__global__ __launch_bounds__(256) void repack_kernel(
    const void* __restrict__ Wselfv, const void* __restrict__ Wneighv,
    const int* __restrict__ flag, ushort* __restrict__ WF)
{
  bool isbf = (*flag != 0);
  int i = blockIdx.x * 256 + threadIdx.x;  // 32768 elements
  int b2 = i & 7;
  int ln = (i >> 3) & 63;
  int nt = (i >> 9) & 7;
  int ks = i >> 12;
  int col = nt * 16 + (ln & 15);
  int k = ks * 32 + ((ln >> 4) << 3) + b2;
  size_t idx = (k < D) ? ((size_t)k * D + col) : ((size_t)(k - D) * D + col);
  const void* W = (k < D) ? Wselfv : Wneighv;
  ushort w;
  if (isbf) w = ((const ushort*)W)[idx];
  else      w = f2bf(((const float*)W)[idx]);
  WF[i] = w;
}

// ---------------- GEMM: out = hcat[n][256] @ WF + b, 256 rows/block ----------------
// 4 waves; wave w owns rows R0+w*64 .. +63 as 4 row-tiles of 16.
// A frag: row = tile*16 + (lane&15), k = ks*32 + (lane>>4)*8 + b
// B frag (LDS, fragment-layout): col = nt*16 + (lane&15), same k
// D frag: col = lane&15, row = 4*(lane>>4) + b   [verified r2]
__global__ __launch_bounds__(256) void gemm_kernel(
    const ushort* __restrict__ hcat, const ushort* __restrict__ WF,
    const void* __restrict__ biasv, const int* __restrict__ flag,
    void* __restrict__ outv, int n)
{
  __shared__ __align__(16) ushort WB[8][8][64][8];  // 64 KB fragment layout
  bool isbf = (*flag != 0);

  int t = threadIdx.x;
#pragma unroll
  for (int i = 0; i < 16; ++i) {
    int idx = i * 256 + t;
    ((bf16x8*)WB)[idx] = ((const bf16x8*)WF)[idx];
  }
  __syncthreads();

  int wave = t >> 6, lane = t & 63;
  int R0 = blockIdx.x * 256 + wave * 64;
  int rl = lane & 15;
  int koff = (lane >> 4) << 3;

  f32x4 acc[4][8];
#pragma unroll
  for (int m = 0; m < 4; ++m)
#pragma unroll
    for (int nt = 0; nt < 8; ++nt) acc[m][nt] = (f32x4)0.0f;

#pragma unroll
  for (int ks = 0; ks < 8; ++ks) {
    bf16x8 a[4];
#pragma unroll
    for (int m = 0; m < 4; ++m) {
      int ar = R0 + m * 16 + rl;
      a[m] = (ar < n)
           ? *reinterpret_cast<const bf16x8*>(hcat + (size_t)ar * 256 + ks * 32 + koff)
           : (bf16x8)0;
    }
#pragma unroll
    for (int nt = 0; nt < 8; ++nt) {
      bf16x8 bfr = *reinterpret_cast<const bf16x8*>(&WB[ks][nt][lane][0]);
#pragma unroll
      for (int m = 0; m < 4; ++m)
        acc[m][nt] = __builtin_amdgcn_mfma_f32_16x16x32_bf16(a[m], bfr, acc[m][nt], 0, 0, 0);
    }
  }

  int orow0 = R0 + ((lane >> 4) << 2);
  int ocol = lane & 15;
#pragma unroll
  for (int nt = 0; nt < 8; ++nt) {
    int co = nt * 16 + ocol;
    float bi = isbf ? bf2f(((const ushort*)biasv)[co]) : ((const float*)biasv)[co];
#pragma unroll
    for (int m = 0; m < 4; ++m) {
#pragma unroll
      for (int b2 = 0; b2 < 4; ++b2) {
        int ro = orow0 + m * 16 + b2;
        if (ro < n) {
          float v = acc[m][nt][b2] + bi;
          if (isbf) ((ushort*)outv)[(size_t)ro * D + co] = f2bf(v);
          else      ((float*)outv)[(size_t)ro * D + co]  = v;
        }
      }
    }
  }
}

extern "C" void kernel_launch(void* const* d_in, const int* in_sizes, int n_in,
                              void* d_out, int out_size, void* d_ws, size_t ws_size,
                              hipStream_t stream) {
  const void* h      = d_in[0];
  const int*  src    = (const int*)d_in[1];
  const int*  dst    = (const int*)d_in[2];
  const void* gamma  = d_in[3];
  const void* beta   = d_in[4];
  const void* Wself  = d_in[5];
  const void* Wneigh = d_in[6];
  const void* bias   = d_in[7];

  int nNodes = in_sizes[0] / D;   // 100000
  int nEdges = in_sizes[1];       // 640000
  int nb = (nNodes + CH - 1) / CH;

  char* ws = (char*)d_ws;
  size_t p = 0;
  auto alloc = [&](size_t bytes) { char* r = ws + p; p = (p + bytes + 255) & ~(size_t)255; return r; };
  ushort* hcat  = (ushort*)alloc((size_t)nNodes * 256 * sizeof(ushort));  // 51.2 MB
  int*   off    = (int*)alloc((size_t)(nNodes + 1) * sizeof(int));
  int*   deg    = (int*)alloc((size_t)nNodes * sizeof(int));
  int*   cursor = (int*)alloc((size_t)nNodes * sizeof(int));
  int*   bsum   = (int*)alloc(1024);
  int*   esrc   = (int*)alloc((size_t)nEdges * sizeof(int));
  ushort* WF    = (ushort*)alloc(32768 * sizeof(ushort));
  int*   flag   = (int*)alloc(256);

  hipMemsetAsync(deg, 0, (size_t)nNodes * sizeof(int), stream);

  detect_kernel<<<1, 256, 0, stream>>>((const unsigned*)h, flag);

  hist_kernel<<<(nEdges + 255) / 256, 256, 0, stream>>>(dst, deg, nEdges);
  scan_local<<<nb, 256, 0, stream>>>(deg, off, bsum, nNodes);
  scan_sums<<<1, 128, 0, stream>>>(bsum, off, nb, nNodes);
  scan_add<<<(nNodes + 255) / 256, 256, 0, stream>>>(off, bsum, cursor, nNodes);
  bucket_kernel<<<(nEdges + 255) / 256, 256, 0, stream>>>(src, dst, cursor, esrc, nEdges);

  ln_kernel<<<(nNodes + 3) / 4, 256, 0, stream>>>(h, gamma, beta, flag, hcat, nNodes);

  repack_kernel<<<128, 256, 0, stream>>>(Wself, Wneigh, flag, WF);

  aggregate_kernel<<<(nNodes + 3) / 4, 256, 0, stream>>>(hcat, off, esrc, nNodes);

  gemm_kernel<<<(nNodes + 255) / 256, 256, 0, stream>>>(hcat, WF, bias, flag, d_out, nNodes);
}

// Round 9
// 179.479 us; speedup vs baseline: 7.5307x; 1.0771x over previous
//
#include <hip/hip_runtime.h>
#include <hip/hip_bf16.h>

#define D 128
#define CH 1024  // scan chunk per block

typedef __attribute__((ext_vector_type(8))) short bf16x8;
typedef __attribute__((ext_vector_type(4))) float f32x4;

__device__ __forceinline__ float bf2f(ushort u) { return __uint_as_float(((unsigned)u) << 16); }
__device__ __forceinline__ ushort f2bf(float f) {
  unsigned x = __float_as_uint(f);
  x += 0x7fffu + ((x >> 16) & 1u);
  return (ushort)(x >> 16);
}

// ---------------- dtype probe: flag=1 if h is packed bf16, 0 if f32 ----------------
__global__ void detect_kernel(const unsigned* __restrict__ h, int* __restrict__ flag) {
  __shared__ int cnt;
  int t = threadIdx.x;
  if (t == 0) cnt = 0;
  __syncthreads();
  unsigned e = (h[t] >> 7) & 0xFFu;
  int ok = (e >= 0x60u && e <= 0x8Fu) ? 1 : 0;
  atomicAdd(&cnt, ok);
  __syncthreads();
  if (t == 0) *flag = (cnt >= 128) ? 1 : 0;
}

// ---------------- LayerNorm (one wave per row) + fused dst-histogram ----------------
__global__ __launch_bounds__(256) void ln_hist_kernel(
    const void* __restrict__ hv, const void* __restrict__ gv,
    const void* __restrict__ bv, const int* __restrict__ flag,
    ushort* __restrict__ hcat, int n,
    const int* __restrict__ dst, int* __restrict__ deg, int nE)
{
  // fused histogram: first ceil(nE/256) blocks each handle 256 edges
  int nbH = (nE + 255) >> 8;
  if (blockIdx.x < (unsigned)nbH) {
    int e = blockIdx.x * 256 + threadIdx.x;
    if (e < nE) atomicAdd(&deg[dst[e]], 1);
  }

  int row = blockIdx.x * 4 + (threadIdx.x >> 6);
  int lane = threadIdx.x & 63;
  if (row < n) {
    bool isbf = (*flag != 0);
    float x0, x1;
    if (isbf) {
      ushort2 u = ((const ushort2*)((const ushort*)hv + (size_t)row * D))[lane];
      x0 = bf2f(u.x); x1 = bf2f(u.y);
    } else {
      float2 u = ((const float2*)((const float*)hv + (size_t)row * D))[lane];
      x0 = u.x; x1 = u.y;
    }
    float s = x0 + x1, sq = x0 * x0 + x1 * x1;
#pragma unroll
    for (int m = 1; m < 64; m <<= 1) { s += __shfl_xor(s, m); sq += __shfl_xor(sq, m); }
    float mu  = s * (1.0f / D);
    float var = sq * (1.0f / D) - mu * mu;
    float inv = rsqrtf(var + 1e-5f);
    float g0, g1, b0, b1;
    if (isbf) {
      ushort2 g = ((const ushort2*)gv)[lane];
      ushort2 b = ((const ushort2*)bv)[lane];
      g0 = bf2f(g.x); g1 = bf2f(g.y); b0 = bf2f(b.x); b1 = bf2f(b.y);
    } else {
      float2 g = ((const float2*)gv)[lane];
      float2 b = ((const float2*)bv)[lane];
      g0 = g.x; g1 = g.y; b0 = b.x; b1 = b.y;
    }
    ushort2 o;
    o.x = f2bf((x0 - mu) * inv * g0 + b0);
    o.y = f2bf((x1 - mu) * inv * g1 + b1);
    ((ushort2*)(hcat + (size_t)row * 256))[lane] = o;
  }
}

// ---------------- CSR scan ----------------
__global__ __launch_bounds__(256) void scan_local(const int* __restrict__ deg,
                                                  int* __restrict__ off,
                                                  int* __restrict__ bsum, int n) {
  __shared__ int sh[256];
  int b = blockIdx.x, t = threadIdx.x;
  int base = b * CH + t * 4;
  int v[4];
#pragma unroll
  for (int i = 0; i < 4; ++i) v[i] = (base + i < n) ? deg[base + i] : 0;
  int tsum = v[0] + v[1] + v[2] + v[3];
  sh[t] = tsum;
  __syncthreads();
#pragma unroll
  for (int d = 1; d < 256; d <<= 1) {
    int x = (t >= d) ? sh[t - d] : 0;
    __syncthreads();
    sh[t] += x;
    __syncthreads();
  }
  if (t == 255) bsum[b] = sh[255];
  int run = sh[t] - tsum;  // exclusive within block
#pragma unroll
  for (int i = 0; i < 4; ++i) {
    if (base + i < n) off[base + i] = run;
    run += v[i];
  }
}

__global__ void scan_sums(int* __restrict__ bsum, int* __restrict__ off, int nb, int n) {
  __shared__ int sh[128];
  int t = threadIdx.x;
  int v = (t < nb) ? bsum[t] : 0;
  sh[t] = v;
  __syncthreads();
#pragma unroll
  for (int d = 1; d < 128; d <<= 1) {
    int x = (t >= d) ? sh[t - d] : 0;
    __syncthreads();
    sh[t] += x;
    __syncthreads();
  }
  if (t < nb) bsum[t] = sh[t] - v;
  if (t == 127) off[n] = sh[127];
}

__global__ __launch_bounds__(256) void scan_add(int* __restrict__ off,
                                                const int* __restrict__ bsum,
                                                int* __restrict__ cursor, int n) {
  int i = blockIdx.x * 256 + threadIdx.x;
  if (i < n) {
    int v = off[i] + bsum[i >> 10];
    off[i] = v;
    cursor[i] = v;
  }
}

// ---------------- bucket (CSR fill) + fused W repack ----------------
// WF[ks][nt][lane][b] = W[k = ks*32 + (lane>>4)*8 + b][col = nt*16 + (lane&15)]
__global__ __launch_bounds__(256) void bucket_repack_kernel(
    const int* __restrict__ src, const int* __restrict__ dst,
    int* __restrict__ cursor, int* __restrict__ esrc, int nE,
    const void* __restrict__ Wselfv, const void* __restrict__ Wneighv,
    const int* __restrict__ flag, ushort* __restrict__ WF)
{
  int nbB = (nE + 255) >> 8;
  int b = blockIdx.x;
  if (b < nbB) {
    int e = b * 256 + threadIdx.x;
    if (e < nE) {
      int p = atomicAdd(&cursor[dst[e]], 1);
      esrc[p] = src[e];
    }
  } else {
    bool isbf = (*flag != 0);
    int i = (b - nbB) * 256 + threadIdx.x;  // 32768 elements
    int b2 = i & 7;
    int ln = (i >> 3) & 63;
    int nt = (i >> 9) & 7;
    int ks = i >> 12;
    int col = nt * 16 + (ln & 15);
    int k = ks * 32 + ((ln >> 4) << 3) + b2;
    size_t idx = (k < D) ? ((size_t)k * D + col) : ((size_t)(k - D) * D + col);
    const void* W = (k < D) ? Wselfv : Wneighv;
    ushort w;
    if (isbf) w = ((const ushort*)W)[idx];
    else      w = f2bf(((const float*)W)[idx]);
    WF[i] = w;
  }
}

// ---------------- Aggregate: one wave per node, unroll-4 gather -> hcat[:, 128:256] ----------------
__global__ __launch_bounds__(256) void aggregate_kernel(
    ushort* __restrict__ hcat, const int* __restrict__ off,
    const int* __restrict__ esrc, int n)
{
  int node = blockIdx.x * 4 + (threadIdx.x >> 6);
  int lane = threadIdx.x & 63;
  if (node >= n) return;
  int d0 = off[node], d1 = off[node + 1];
  float a0 = 0.f, a1 = 0.f;
  int j = d0;
  for (; j + 3 < d1; j += 4) {
    int s0 = esrc[j], s1 = esrc[j + 1], s2 = esrc[j + 2], s3 = esrc[j + 3];
    ushort2 u0 = ((const ushort2*)(hcat + (size_t)s0 * 256))[lane];
    ushort2 u1 = ((const ushort2*)(hcat + (size_t)s1 * 256))[lane];
    ushort2 u2 = ((const ushort2*)(hcat + (size_t)s2 * 256))[lane];
    ushort2 u3 = ((const ushort2*)(hcat + (size_t)s3 * 256))[lane];
    a0 += (bf2f(u0.x) + bf2f(u1.x)) + (bf2f(u2.x) + bf2f(u3.x));
    a1 += (bf2f(u0.y) + bf2f(u1.y)) + (bf2f(u2.y) + bf2f(u3.y));
  }
  for (; j < d1; ++j) {
    int s0 = esrc[j];
    ushort2 u0 = ((const ushort2*)(hcat + (size_t)s0 * 256))[lane];
    a0 += bf2f(u0.x);
    a1 += bf2f(u0.y);
  }
  int dg = d1 - d0;
  float invd = 1.0f / (float)(dg > 1 ? dg : 1);
  ushort2 o;
  o.x = f2bf(a0 * invd);
  o.y = f2bf(a1 * invd);
  ((ushort2*)(hcat + (size_t)node * 256 + D))[lane] = o;
}

// ---------------- GEMM: out = hcat[n][256] @ W + b. NO LDS. ----------------
// Block = 4 waves, 64 rows. Wave w owns cols nt = {2w, 2w+1}; its 16 B-fragments
// live persistently in 64 VGPRs (loaded once from pre-packed WF, L2-resident).
// A frag: row = m*16 + (lane&15), k = ks*32 + (lane>>4)*8 + b
// D frag: col = lane&15, row = 4*(lane>>4) + b   [verified r2]
__global__ __launch_bounds__(256) void gemm_kernel(
    const ushort* __restrict__ hcat, const ushort* __restrict__ WF,
    const void* __restrict__ biasv, const int* __restrict__ flag,
    void* __restrict__ outv, int n)
{
  bool isbf = (*flag != 0);
  int t = threadIdx.x;
  int wave = t >> 6, lane = t & 63;

  // persistent B fragments: 8 ks x 2 nt
  bf16x8 bfr[8][2];
#pragma unroll
  for (int ks = 0; ks < 8; ++ks)
#pragma unroll
    for (int q = 0; q < 2; ++q) {
      int nt = wave * 2 + q;
      bfr[ks][q] = ((const bf16x8*)WF)[(ks * 8 + nt) * 64 + lane];
    }

  int R0 = blockIdx.x * 64;
  int rl = lane & 15;
  int koff = (lane >> 4) << 3;

  f32x4 acc[4][2];
#pragma unroll
  for (int m = 0; m < 4; ++m)
#pragma unroll
    for (int q = 0; q < 2; ++q) acc[m][q] = (f32x4)0.0f;

#pragma unroll
  for (int ks = 0; ks < 8; ++ks) {
    bf16x8 a[4];
#pragma unroll
    for (int m = 0; m < 4; ++m) {
      int ar = R0 + m * 16 + rl;
      a[m] = (ar < n)
           ? *reinterpret_cast<const bf16x8*>(hcat + (size_t)ar * 256 + ks * 32 + koff)
           : (bf16x8)0;
    }
#pragma unroll
    for (int q = 0; q < 2; ++q)
#pragma unroll
      for (int m = 0; m < 4; ++m)
        acc[m][q] = __builtin_amdgcn_mfma_f32_16x16x32_bf16(a[m], bfr[ks][q], acc[m][q], 0, 0, 0);
  }

  int orow0 = R0 + ((lane >> 4) << 2);
  int ocol = lane & 15;
#pragma unroll
  for (int q = 0; q < 2; ++q) {
    int co = (wave * 2 + q) * 16 + ocol;
    float bi = isbf ? bf2f(((const ushort*)biasv)[co]) : ((const float*)biasv)[co];
#pragma unroll
    for (int m = 0; m < 4; ++m) {
#pragma unroll
      for (int b2 = 0; b2 < 4; ++b2) {
        int ro = orow0 + m * 16 + b2;
        if (ro < n) {
          float v = acc[m][q][b2] + bi;
          if (isbf) ((ushort*)outv)[(size_t)ro * D + co] = f2bf(v);
          else      ((float*)outv)[(size_t)ro * D + co]  = v;
        }
      }
    }
  }
}

extern "C" void kernel_launch(void* const* d_in, const int* in_sizes, int n_in,
                              void* d_out, int out_size, void* d_ws, size_t ws_size,
                              hipStream_t stream) {
  const void* h      = d_in[0];
  const int*  src    = (const int*)d_in[1];
  const int*  dst    = (const int*)d_in[2];
  const void* gamma  = d_in[3];
  const void* beta   = d_in[4];
  const void* Wself  = d_in[5];
  const void* Wneigh = d_in[6];
  const void* bias   = d_in[7];

  int nNodes = in_sizes[0] / D;   // 100000
  int nEdges = in_sizes[1];       // 640000
  int nb = (nNodes + CH - 1) / CH;

  char* ws = (char*)d_ws;
  size_t p = 0;
  auto alloc = [&](size_t bytes) { char* r = ws + p; p = (p + bytes + 255) & ~(size_t)255; return r; };
  ushort* hcat  = (ushort*)alloc((size_t)nNodes * 256 * sizeof(ushort));  // 51.2 MB
  int*   off    = (int*)alloc((size_t)(nNodes + 1) * sizeof(int));
  int*   deg    = (int*)alloc((size_t)nNodes * sizeof(int));
  int*   cursor = (int*)alloc((size_t)nNodes * sizeof(int));
  int*   bsum   = (int*)alloc(1024);
  int*   esrc   = (int*)alloc((size_t)nEdges * sizeof(int));
  ushort* WF    = (ushort*)alloc(32768 * sizeof(ushort));
  int*   flag   = (int*)alloc(256);

  hipMemsetAsync(deg, 0, (size_t)nNodes * sizeof(int), stream);

  detect_kernel<<<1, 256, 0, stream>>>((const unsigned*)h, flag);

  // LN + fused histogram
  ln_hist_kernel<<<(nNodes + 3) / 4, 256, 0, stream>>>(h, gamma, beta, flag, hcat,
                                                       nNodes, dst, deg, nEdges);

  scan_local<<<nb, 256, 0, stream>>>(deg, off, bsum, nNodes);
  scan_sums<<<1, 128, 0, stream>>>(bsum, off, nb, nNodes);
  scan_add<<<(nNodes + 255) / 256, 256, 0, stream>>>(off, bsum, cursor, nNodes);

  // bucket + fused W repack
  int nbB = (nEdges + 255) / 256;
  bucket_repack_kernel<<<nbB + 128, 256, 0, stream>>>(src, dst, cursor, esrc, nEdges,
                                                      Wself, Wneigh, flag, WF);

  aggregate_kernel<<<(nNodes + 3) / 4, 256, 0, stream>>>(hcat, off, esrc, nNodes);

  gemm_kernel<<<(nNodes + 63) / 64, 256, 0, stream>>>(hcat, WF, bias, flag, d_out, nNodes);
}